// Round 3
// baseline (158.265 us; speedup 1.0000x reference)
//
#include <hip/hip_runtime.h>

// Problem constants (from reference): B=256, L=512, F=128, ids in [0,1024).
#define B_   256
#define L_   512
#define F_   128
#define NID  1024
#define NTAB 513   // counts range 0..512 inclusive

// Native clang vector type — required by __builtin_nontemporal_store
// (HIP's float4 is a class and is rejected by the builtin).
typedef float f32x4 __attribute__((ext_vector_type(4)));

// ---------------------------------------------------------------------------
// Kernel A: build lookup table G[c][g] = b2[g] + sum_f relu(c*W1[f]+b1[f]) * W2[g][f]
// for every possible integer count c in [0, 512]. One block per c, 128 threads.
// out[b,l,:] = G[c0] + G[c1]  (b2 folded into G; exactly 2 channels, symmetric).
// ---------------------------------------------------------------------------
__global__ void build_table_kernel(const float* __restrict__ W1,
                                   const float* __restrict__ b1,
                                   const float* __restrict__ W2,
                                   const float* __restrict__ b2,
                                   float* __restrict__ G) {
    __shared__ float h[F_];
    const int c = blockIdx.x;   // 0..512
    const int g = threadIdx.x;  // 0..127
    // h[f] = relu(c * W1[f] + b1[f])
    h[g] = fmaxf(fmaf((float)c, W1[g], b1[g]), 0.0f);
    __syncthreads();
    float acc = b2[g];
    const f32x4* __restrict__ w2row = reinterpret_cast<const f32x4*>(W2 + g * F_);
    const f32x4* __restrict__ h4    = reinterpret_cast<const f32x4*>(h);
#pragma unroll
    for (int k = 0; k < F_ / 4; ++k) {
        f32x4 w  = w2row[k];
        f32x4 hh = h4[k];           // LDS broadcast across the wave — conflict-free
        acc = fmaf(hh.x, w.x, acc);
        acc = fmaf(hh.y, w.y, acc);
        acc = fmaf(hh.z, w.z, acc);
        acc = fmaf(hh.w, w.w, acc);
    }
    G[c * F_ + g] = acc;
}

// ---------------------------------------------------------------------------
// Kernel B: per-batch-row histograms + count lookup.
// One block per batch row b, 512 threads (one per sequence position).
// Writes packed counts:  cnts[b*L+l]        = c_src0 | (c_src1 << 16)   (src query)
//                        cnts[B*L + b*L+l]  = c_dst0 | (c_dst1 << 16)   (dst query)
// Masking: query id == 0 -> both counts 0 (matches reference's where(); the
// downstream encode still runs on c=0, giving G[0]+G[0] — same as reference).
// ---------------------------------------------------------------------------
__global__ void count_kernel(const int* __restrict__ src,
                             const int* __restrict__ dst,
                             unsigned int* __restrict__ cnts) {
    __shared__ int hs[NID];
    __shared__ int hd[NID];
    const int b = blockIdx.x;
    const int t = threadIdx.x;  // 0..511
    hs[t] = 0; hs[t + 512] = 0;
    hd[t] = 0; hd[t + 512] = 0;
    __syncthreads();
    const int s = src[b * L_ + t] & (NID - 1);
    const int d = dst[b * L_ + t] & (NID - 1);
    atomicAdd(&hs[s], 1);
    atomicAdd(&hd[d], 1);
    __syncthreads();
    // channel order is irrelevant downstream (out = G[c0]+G[c1], symmetric)
    unsigned int cs = (s != 0) ? ((unsigned int)hs[s] | ((unsigned int)hd[s] << 16)) : 0u;
    unsigned int cd = (d != 0) ? ((unsigned int)hs[d] | ((unsigned int)hd[d] << 16)) : 0u;
    cnts[b * L_ + t] = cs;
    cnts[B_ * L_ + b * L_ + t] = cd;
}

// ---------------------------------------------------------------------------
// Kernel C: streaming gather-write.  out float4 #i corresponds to
//   bl  = i >> 5   (index into cnts, covering [src rows | dst rows])
//   f4  = i & 31   (position along F)
// Pure write-bound: 128 MiB nontemporal stores; table reads are cache-resident
// (real counts concentrate on 0..~6 -> G working set a few KB).
// ---------------------------------------------------------------------------
__global__ void write_out_kernel(const float* __restrict__ G,
                                 const unsigned int* __restrict__ cnts,
                                 f32x4* __restrict__ out,
                                 int total4) {
    const int stride = gridDim.x * blockDim.x;
    for (int i = blockIdx.x * blockDim.x + threadIdx.x; i < total4; i += stride) {
        const int f4 = i & 31;
        const int bl = i >> 5;
        const unsigned int pc = cnts[bl];         // broadcast across 32 lanes -> cache hit
        const int c0 = (int)(pc & 0xFFFFu);
        const int c1 = (int)(pc >> 16);
        f32x4 g0 = *reinterpret_cast<const f32x4*>(G + c0 * F_ + f4 * 4);
        f32x4 g1 = *reinterpret_cast<const f32x4*>(G + c1 * F_ + f4 * 4);
        f32x4 r = g0 + g1;
        __builtin_nontemporal_store(r, &out[i]);  // write-once stream, bypass cache
    }
}

extern "C" void kernel_launch(void* const* d_in, const int* in_sizes, int n_in,
                              void* d_out, int out_size, void* d_ws, size_t ws_size,
                              hipStream_t stream) {
    const int*   src = (const int*)  d_in[0];   // (B, L) int32
    const int*   dst = (const int*)  d_in[1];   // (B, L) int32
    const float* W1  = (const float*)d_in[2];   // (F, 1)
    const float* b1  = (const float*)d_in[3];   // (F,)
    const float* W2  = (const float*)d_in[4];   // (F, F)
    const float* b2  = (const float*)d_in[5];   // (F,)
    float* out = (float*)d_out;                 // [src_feat | dst_feat], each (B,L,F) f32

    // Workspace layout: G table (513*128 f32 = 262,656 B), then packed counts
    // (2*B*L u32 = 1 MiB). Total ~1.25 MiB.
    float* G = (float*)d_ws;
    unsigned int* cnts =
        (unsigned int*)((char*)d_ws + (size_t)NTAB * F_ * sizeof(float));

    build_table_kernel<<<NTAB, F_, 0, stream>>>(W1, b1, W2, b2, G);
    count_kernel<<<B_, L_, 0, stream>>>(src, dst, cnts);

    const int total4 = 2 * B_ * L_ * (F_ / 4);  // 8,388,608 float4s = 128 MiB
    write_out_kernel<<<2048, 256, 0, stream>>>(G, cnts, (f32x4*)out, total4);
}

// Round 5
// 151.599 us; speedup vs baseline: 1.0440x; 1.0440x over previous
//
#include <hip/hip_runtime.h>

// Problem constants (from reference): B=256, L=512, F=128, ids in [0,1024).
#define B_   256
#define L_   512
#define F_   128
#define NID  1024
#define NTAB 513   // counts range 0..512 inclusive

// Native clang vector type (also valid for plain loads/stores).
typedef float f32x4 __attribute__((ext_vector_type(4)));

// ---------------------------------------------------------------------------
// Kernel 1 (fused prep): blocks [0,129) build the 513x128 lookup table
//   G[c][g] = b2[g] + sum_f relu(c*W1[f]+b1[f]) * W2[g][f]   (4 c's per block)
// blocks [129, 129+256) build per-batch-row histograms and emit packed counts:
//   cnts[b*L+l]       = c_src_in_src | (c_src_in_dst << 16)
//   cnts[B*L+b*L+l]   = c_dst_in_src | (c_dst_in_dst << 16)
// Masking: query id == 0 -> both counts 0 (downstream gives G[0]+G[0], which
// matches the reference's where() + encode-on-zeros).
// ---------------------------------------------------------------------------
#define TBLK 129   // ceil(513/4) table blocks

__global__ void prep_kernel(const int* __restrict__ src,
                            const int* __restrict__ dst,
                            const float* __restrict__ W1,
                            const float* __restrict__ b1,
                            const float* __restrict__ W2,
                            const float* __restrict__ b2,
                            float* __restrict__ G,
                            unsigned int* __restrict__ cnts) {
    __shared__ float h[4][F_];   // table path (2 KB)
    __shared__ int hs[NID];      // hist path  (4 KB)
    __shared__ int hd[NID];      //            (4 KB)
    const int blk = blockIdx.x;
    const int t   = threadIdx.x;  // 0..511

    if (blk < TBLK) {
        // ---- lookup-table path: c = blk*4 + (t>>7), g = t&127 ----
        const int cl = t >> 7;
        const int g  = t & 127;
        const int c  = blk * 4 + cl;
        if (c < NTAB) h[cl][g] = fmaxf(fmaf((float)c, W1[g], b1[g]), 0.0f);
        __syncthreads();
        if (c < NTAB) {
            float acc = b2[g];
            const f32x4* __restrict__ w2row = reinterpret_cast<const f32x4*>(W2 + g * F_);
            const f32x4* __restrict__ h4    = reinterpret_cast<const f32x4*>(h[cl]);
#pragma unroll
            for (int k = 0; k < F_ / 4; ++k) {
                f32x4 w  = w2row[k];   // L1/L2-resident after first block
                f32x4 hh = h4[k];      // LDS broadcast — conflict-free
                acc = fmaf(hh.x, w.x, acc);
                acc = fmaf(hh.y, w.y, acc);
                acc = fmaf(hh.z, w.z, acc);
                acc = fmaf(hh.w, w.w, acc);
            }
            G[c * F_ + g] = acc;
        }
    } else {
        // ---- histogram path: one block per batch row ----
        const int b = blk - TBLK;
        hs[t] = 0; hs[t + 512] = 0;
        hd[t] = 0; hd[t + 512] = 0;
        __syncthreads();
        const int s = src[b * L_ + t] & (NID - 1);
        const int d = dst[b * L_ + t] & (NID - 1);
        atomicAdd(&hs[s], 1);
        atomicAdd(&hd[d], 1);
        __syncthreads();
        // channel order irrelevant downstream (out = G[c0]+G[c1], symmetric)
        unsigned int cs = (s != 0) ? ((unsigned int)hs[s] | ((unsigned int)hd[s] << 16)) : 0u;
        unsigned int cd = (d != 0) ? ((unsigned int)hs[d] | ((unsigned int)hd[d] << 16)) : 0u;
        cnts[b * L_ + t] = cs;
        cnts[B_ * L_ + b * L_ + t] = cd;
    }
}

// ---------------------------------------------------------------------------
// Kernel 2: streaming gather-write.  out f32x4 #i:
//   bl = i >> 5  (index into cnts, covering [src rows | dst rows])
//   f4 = i & 31  (position along F)
// Plain stores (write-allocate path) — the harness's own 512 MiB fills hit
// 6.4 TB/s on exactly this path, so it is the known-fast store mode.
// ---------------------------------------------------------------------------
__global__ void write_out_kernel(const float* __restrict__ G,
                                 const unsigned int* __restrict__ cnts,
                                 f32x4* __restrict__ out,
                                 int total4) {
    const int stride = gridDim.x * blockDim.x;
    for (int i = blockIdx.x * blockDim.x + threadIdx.x; i < total4; i += stride) {
        const int f4 = i & 31;
        const int bl = i >> 5;
        const unsigned int pc = cnts[bl];   // uniform across 32 lanes -> 1 req + broadcast
        const int c0 = (int)(pc & 0xFFFFu);
        const int c1 = (int)(pc >> 16);
        f32x4 g0 = *reinterpret_cast<const f32x4*>(G + c0 * F_ + f4 * 4);
        f32x4 g1 = *reinterpret_cast<const f32x4*>(G + c1 * F_ + f4 * 4);
        out[i] = g0 + g1;                   // coalesced 16B/lane streaming store
    }
}

extern "C" void kernel_launch(void* const* d_in, const int* in_sizes, int n_in,
                              void* d_out, int out_size, void* d_ws, size_t ws_size,
                              hipStream_t stream) {
    const int*   src = (const int*)  d_in[0];   // (B, L) int32
    const int*   dst = (const int*)  d_in[1];   // (B, L) int32
    const float* W1  = (const float*)d_in[2];   // (F, 1)
    const float* b1  = (const float*)d_in[3];   // (F,)
    const float* W2  = (const float*)d_in[4];   // (F, F)
    const float* b2  = (const float*)d_in[5];   // (F,)
    float* out = (float*)d_out;                 // [src_feat | dst_feat], each (B,L,F) f32

    // Workspace: G table (513*128 f32 = 262,656 B), then packed counts (2*B*L u32).
    float* G = (float*)d_ws;
    unsigned int* cnts =
        (unsigned int*)((char*)d_ws + (size_t)NTAB * F_ * sizeof(float));

    prep_kernel<<<TBLK + B_, 512, 0, stream>>>(src, dst, W1, b1, W2, b2, G, cnts);

    const int total4 = 2 * B_ * L_ * (F_ / 4);  // 8,388,608 f32x4 = 128 MiB
    write_out_kernel<<<2048, 256, 0, stream>>>(G, cnts, (f32x4*)out, total4);
}